// Round 7
// baseline (222.718 us; speedup 1.0000x reference)
//
#include <hip/hip_runtime.h>
#include <stdint.h>

#define B_ 4
#define T_ 2048
#define C_ 768
#define H_ 12
#define D_ 64
#define BT_ (B_*T_)
#define C3_ (3*C_)
#define FMIN_ (-3.402823466e38f)
// 0.125 * log2(e): Q prescale so QK^T scores are in log2 units
#define QSCALE_ (0.18033688f)

typedef __attribute__((ext_vector_type(8))) short short8;
typedef __attribute__((ext_vector_type(4))) short s16x4;
typedef __attribute__((ext_vector_type(4))) float f32x4;

// async global->LDS DMA, 16B per lane; LDS dest = wave-uniform base + lane*16
#define GLDS16(g, l) __builtin_amdgcn_global_load_lds( \
    (const __attribute__((address_space(1))) void*)(g), \
    (__attribute__((address_space(3))) void*)(l), 16, 0, 0)

__device__ __forceinline__ float bf2f(unsigned short u) {
    union { unsigned int i; float f; } v; v.i = ((unsigned int)u) << 16; return v.f;
}
__device__ __forceinline__ unsigned short f2bf(float f) {
    union { float ff; unsigned int i; } v; v.ff = f;
    unsigned int r = v.i + 0x7fffu + ((v.i >> 16) & 1u);
    return (unsigned short)(r >> 16);
}
// packed f32x2 -> bf16x2 (RNE), single HW instr
__device__ __forceinline__ unsigned int cvtpk(float lo, float hi) {
    unsigned int r;
    asm("v_cvt_pk_bf16_f32 %0, %1, %2" : "=v"(r) : "v"(lo), "v"(hi));
    return r;
}
__device__ __forceinline__ float ldf(const void* p, size_t i, int isbf) {
    return isbf ? bf2f(((const unsigned short*)p)[i]) : ((const float*)p)[i];
}

// ---------------- dtype detection, per tensor ----------------
// flags[0..4]: 1 if {x,wqkv,bqkv,wproj,bproj} is bf16, 0 if f32
// flags[5]: mask mode: 1=int32, 2=f32, 0=uint8/bool
__global__ void k_detect(const void* x, const void* wqkv, const void* bqkv,
                         const void* wproj, const void* bproj, const void* mask,
                         int* flags) {
    __shared__ int cnt[8];
    int tid = threadIdx.x;
    if (tid < 8) cnt[tid] = 0;
    __syncthreads();
    const void* ptrs[5] = {x, wqkv, bqkv, wproj, bproj};
#pragma unroll
    for (int t = 0; t < 5; ++t) {
        unsigned short u = ((const unsigned short*)ptrs[t])[2 * tid];
        int e = (u >> 7) & 0xff;
        if (e >= 100 && e <= 140) atomicAdd(&cnt[t], 1);
    }
    if (tid < 64) {
        unsigned int d = ((const unsigned int*)mask)[tid];
        if (d <= 1u) atomicAdd(&cnt[5], 1);
        if (d == 0u || d == 0x3f800000u) atomicAdd(&cnt[6], 1);
    }
    __syncthreads();
    if (tid < 5) flags[tid] = (cnt[tid] >= 128) ? 1 : 0;
    if (tid == 5) flags[5] = (cnt[5] == 64) ? 1 : ((cnt[6] == 64) ? 2 : 0);
}

// ---------------- canonicalize x -> bf16 ----------------
__global__ void k_canon_x(const void* x, unsigned short* xb, const int* flags) {
    const int n8 = BT_ * C_ / 8;
    int i = blockIdx.x * blockDim.x + threadIdx.x;
    if (i >= n8) return;
    if (flags[0]) {
        ((int4*)xb)[i] = ((const int4*)x)[i];
    } else {
        const float4* xf = (const float4*)x;
        float4 a = xf[2*i], b = xf[2*i+1];
        short8 o;
        o[0]=(short)f2bf(a.x); o[1]=(short)f2bf(a.y); o[2]=(short)f2bf(a.z); o[3]=(short)f2bf(a.w);
        o[4]=(short)f2bf(b.x); o[5]=(short)f2bf(b.y); o[6]=(short)f2bf(b.z); o[7]=(short)f2bf(b.w);
        *(short8*)&xb[8*i] = o;
    }
}

// ---------------- transpose weight [K][N] -> bf16 [N][K] ----------------
__global__ void k_canon_wT(const void* src, unsigned short* dst, const int* flags,
                           int fidx, int K, int N) {
    __shared__ float tile[32][33];
    int mode = flags[fidx];
    int n0 = blockIdx.x * 32, k0 = blockIdx.y * 32;
    int tx = threadIdx.x & 31, ty = threadIdx.x >> 5;
    for (int r = ty; r < 32; r += 8) {
        size_t idx = (size_t)(k0 + r) * N + (n0 + tx);
        tile[r][tx] = mode ? bf2f(((const unsigned short*)src)[idx])
                           : ((const float*)src)[idx];
    }
    __syncthreads();
    for (int r = ty; r < 32; r += 8) {
        dst[(size_t)(n0 + r) * K + k0 + tx] = f2bf(tile[tx][r]);
    }
}

// ---------------- biases (f32) + mask bias ----------------
__global__ void k_canon_small(const void* bqkv, const void* bproj, const void* mask,
                              float* bqkvF, float* bprojF, float* maskF, const int* flags) {
    int i = blockIdx.x * blockDim.x + threadIdx.x;
    if (i < C3_) bqkvF[i] = ldf(bqkv, i, flags[2]);
    if (i < C_)  bprojF[i] = ldf(bproj, i, flags[4]);
    if (i < BT_) {
        int mm = flags[5];
        int mv;
        if (mm == 1)      mv = ((const int*)mask)[i] != 0;
        else if (mm == 2) mv = ((const float*)mask)[i] != 0.0f;
        else              mv = ((const unsigned char*)mask)[i] != 0;
        maskF[i] = mv ? FMIN_ : 0.0f;
    }
}

// ---------------- bf16 MFMA GEMM: C = A[M][K] * Bt[N][K]^T + bias ----------------
// Staging via global_load_lds (16B/lane DMA), linear LDS [128][64].
// EPI 0: scatter into Q([B,H,T,D], *QSCALE), K([B,H,T,D]), V^T([B,H,D,T]), bf16
// EPI 1: f32 [M][N] into d_out
template<int EPI>
__global__ __launch_bounds__(256) void k_gemm(
        const unsigned short* __restrict__ A, const unsigned short* __restrict__ Bt,
        const float* __restrict__ bias,
        void* __restrict__ out0, unsigned short* __restrict__ out1,
        unsigned short* __restrict__ out2,
        int M, int N, int K) {
    __shared__ __align__(16) unsigned short la[128*64];
    __shared__ __align__(16) unsigned short lb[128*64];
    const int tid = threadIdx.x;
    const int w = tid >> 6, lane = tid & 63, lr = lane & 15, lg = lane >> 4;
    const int wm = (w >> 1) * 64, wn = (w & 1) * 64;
    const int n0 = blockIdx.x * 128, m0 = blockIdx.y * 128;
    f32x4 acc[4][4] = {};
    for (int k0 = 0; k0 < K; k0 += 64) {
        // stage A,B tiles: 16 chunks of 1KB each (8 rows x 64 k), 4 per wave
#pragma unroll
        for (int c = 0; c < 4; ++c) {
            const int chunk = w * 4 + c;
            const int row = chunk * 8 + (lane >> 3);
            const int cb8 = (lane & 7) * 8;
            GLDS16(&A[(size_t)(m0+row)*K + k0 + cb8], &la[chunk*512]);
            GLDS16(&Bt[(size_t)(n0+row)*K + k0 + cb8], &lb[chunk*512]);
        }
        __syncthreads();   // implicit vmcnt(0) drains the DMA
#pragma unroll
        for (int ks = 0; ks < 64; ks += 32) {
            short8 af[4], bfr[4];
#pragma unroll
            for (int i = 0; i < 4; ++i)
                af[i] = *(const short8*)&la[(wm + i*16 + lr)*64 + ks + lg*8];
#pragma unroll
            for (int j = 0; j < 4; ++j)
                bfr[j] = *(const short8*)&lb[(wn + j*16 + lr)*64 + ks + lg*8];
#pragma unroll
            for (int i = 0; i < 4; ++i)
#pragma unroll
                for (int j = 0; j < 4; ++j)
                    acc[i][j] = __builtin_amdgcn_mfma_f32_16x16x32_bf16(af[i], bfr[j], acc[i][j], 0, 0, 0);
        }
        __syncthreads();   // all reads done before next-tile DMA
    }
#pragma unroll
    for (int i = 0; i < 4; ++i)
#pragma unroll
        for (int j = 0; j < 4; ++j)
#pragma unroll
            for (int r = 0; r < 4; ++r) {
                int row = m0 + wm + i*16 + lg*4 + r;
                int col = n0 + wn + j*16 + lr;
                float v = acc[i][j][r] + bias[col];
                if (EPI == 0) {
                    int seg = col / C_;
                    int c = col - seg * C_;
                    int h = c >> 6, d = c & 63;
                    int b = row >> 11, t = row & (T_ - 1);
                    if (seg == 0)      ((unsigned short*)out0)[(((size_t)b*H_ + h)*T_ + t)*D_ + d] = f2bf(v * QSCALE_);
                    else if (seg == 1) out1[(((size_t)b*H_ + h)*T_ + t)*D_ + d] = f2bf(v);
                    else               out2[(((size_t)b*H_ + h)*D_ + d)*T_ + t] = f2bf(v);
                } else {
                    ((float*)out0)[(size_t)row * N + col] = v;
                }
            }
}

// ---------------- flash attention, swapped QK^T, log2 softmax, dbuf staging ----------------
// Q[B,H,T,D] (pre-scaled 0.125*log2e), K[B,H,T,D], V^T[B,H,D,T], all bf16.
// Block = 4 waves; wave owns 32 q rows. KVBLK = 64. Double-buffered K/V/mask:
// next-tile global loads issued BEFORE compute (latency hides under MFMA),
// LDS writes AFTER compute, single barrier per tile.
__global__ __launch_bounds__(256) void k_attn(
        const unsigned short* __restrict__ Q, const unsigned short* __restrict__ Kt,
        const unsigned short* __restrict__ Vt, const float* __restrict__ maskF,
        unsigned short* __restrict__ AO) {
    __shared__ __align__(16) unsigned short lk[2][64*72];
    __shared__ __align__(16) unsigned short lv[2][64*72];
    __shared__ __align__(16) float lmb[2][64];
    const int tid = threadIdx.x;
    const int w = tid >> 6, lane = tid & 63, lr = lane & 15, lg = lane >> 4;
    // bijective XCD swizzle: 768 blocks = 8 XCD x 96; 16 consecutive share one bh's K/V
    const int per = gridDim.x >> 3;
    const int swz = (blockIdx.x & 7) * per + (blockIdx.x >> 3);
    const int bh = swz >> 4, qt = swz & 15;
    const int b = bh / H_, h = bh - b * H_;
    const int qbase = qt * 128 + w * 32;
    const unsigned short* Qb = Q  + (size_t)bh * T_ * D_;
    const unsigned short* Kb = Kt + (size_t)bh * T_ * D_;
    const unsigned short* Vb = Vt + (size_t)bh * D_ * T_;

    // staging coords (two 256-thread passes)
    const int r0 = tid >> 3, c8 = (tid & 7) * 8;
    const int r1 = r0 + 32;

    // Q as B-operand: lane holds col q=qc*16+lr, k-elems d = dh*32+lg*8..+7
    short8 qf[2][2];
#pragma unroll
    for (int qc = 0; qc < 2; ++qc)
#pragma unroll
        for (int dh = 0; dh < 2; ++dh)
            qf[qc][dh] = *(const short8*)&Qb[(size_t)(qbase + qc*16 + lr) * D_ + dh*32 + lg*8];

    // prologue: stage tile 0 into buf 0
    *(short8*)&lk[0][r0*72 + c8] = *(const short8*)&Kb[(size_t)r0 * D_ + c8];
    *(short8*)&lv[0][r0*72 + c8] = *(const short8*)&Vb[(size_t)r0 * T_ + c8];
    *(short8*)&lk[0][r1*72 + c8] = *(const short8*)&Kb[(size_t)r1 * D_ + c8];
    *(short8*)&lv[0][r1*72 + c8] = *(const short8*)&Vb[(size_t)r1 * T_ + c8];
    if (tid < 64) lmb[0][tid] = maskF[b*T_ + tid];
    __syncthreads();

    f32x4 ot[4][2] = {};           // O^T[dblk][qc]
    float m[2] = {-INFINITY, -INFINITY}, l[2] = {0.0f, 0.0f};
    int cur = 0;

    for (int kt = 0; kt < T_; kt += 64) {
        const int nxt = kt + 64;
        const bool has = nxt < T_;
        // issue next-tile global loads early (hide latency under compute)
        short8 nk0, nk1, nv0, nv1; float nm = 0.0f;
        if (has) {
            nk0 = *(const short8*)&Kb[(size_t)(nxt + r0) * D_ + c8];
            nv0 = *(const short8*)&Vb[(size_t)r0 * T_ + nxt + c8];
            nk1 = *(const short8*)&Kb[(size_t)(nxt + r1) * D_ + c8];
            nv1 = *(const short8*)&Vb[(size_t)r1 * T_ + nxt + c8];
            if (tid < 64) nm = maskF[b*T_ + nxt + tid];
        }

        // C-init = mask bias per key (shared by both qc); mask add is free+exact
        f32x4 st[4][2];
#pragma unroll
        for (int kf = 0; kf < 4; ++kf) {
            f32x4 mi = *(const f32x4*)&lmb[cur][kf*16 + lg*4];
            st[kf][0] = mi;
            st[kf][1] = mi;
        }
        // S^T = K Q^T + mask
#pragma unroll
        for (int dh = 0; dh < 2; ++dh) {
            short8 kfr[4];
#pragma unroll
            for (int kf = 0; kf < 4; ++kf)
                kfr[kf] = *(const short8*)&lk[cur][(kf*16 + lr)*72 + dh*32 + lg*8];
#pragma unroll
            for (int kf = 0; kf < 4; ++kf)
#pragma unroll
                for (int qc = 0; qc < 2; ++qc)
                    st[kf][qc] = __builtin_amdgcn_mfma_f32_16x16x32_bf16(kfr[kf], qf[qc][dh], st[kf][qc], 0, 0, 0);
        }
        // online softmax per qc (row = q = qc*16+lr; spread over 4 lanes lg)
#pragma unroll
        for (int qc = 0; qc < 2; ++qc) {
            float t0 = fmaxf(fmaxf(st[0][qc][0], st[0][qc][1]), st[0][qc][2]);
            float t1 = fmaxf(fmaxf(st[0][qc][3], st[1][qc][0]), st[1][qc][1]);
            float t2 = fmaxf(fmaxf(st[1][qc][2], st[1][qc][3]), st[2][qc][0]);
            float t3 = fmaxf(fmaxf(st[2][qc][1], st[2][qc][2]), st[2][qc][3]);
            float t4 = fmaxf(fmaxf(st[3][qc][0], st[3][qc][1]), st[3][qc][2]);
            float tm = fmaxf(fmaxf(t0, t1), fmaxf(fmaxf(t2, t3), fmaxf(t4, st[3][qc][3])));
            tm = fmaxf(tm, __shfl_xor(tm, 16));
            tm = fmaxf(tm, __shfl_xor(tm, 32));
            // defer-max: skip rescale while max growth <= 8 (p bounded by 2^8)
            if (!__all(tm - m[qc] <= 8.0f)) {
                float mn = fmaxf(m[qc], tm);
                float sc = __builtin_amdgcn_exp2f(m[qc] - mn);
                m[qc] = mn;
                l[qc] *= sc;
#pragma unroll
                for (int dblk = 0; dblk < 4; ++dblk) ot[dblk][qc] *= sc;
            }
            float mr = m[qc];
            float ps = 0.0f;
#pragma unroll
            for (int kf = 0; kf < 4; ++kf)
#pragma unroll
                for (int r = 0; r < 4; ++r) {
                    float p = __builtin_amdgcn_exp2f(st[kf][qc][r] - mr);
                    st[kf][qc][r] = p;
                    ps += p;
                }
            l[qc] += ps;
        }
        // pack P in-lane into relabeled B-fragments: pb[qc][ks]
        union PU { unsigned int u[4]; short8 s; };
        PU pb[2][2];
#pragma unroll
        for (int qc = 0; qc < 2; ++qc)
#pragma unroll
            for (int ks = 0; ks < 2; ++ks) {
                pb[qc][ks].u[0] = cvtpk(st[2*ks][qc][0],   st[2*ks][qc][1]);
                pb[qc][ks].u[1] = cvtpk(st[2*ks][qc][2],   st[2*ks][qc][3]);
                pb[qc][ks].u[2] = cvtpk(st[2*ks+1][qc][0], st[2*ks+1][qc][1]);
                pb[qc][ks].u[3] = cvtpk(st[2*ks+1][qc][2], st[2*ks+1][qc][3]);
            }
        // O^T += V^T P^T with matching slot relabel
#pragma unroll
        for (int ks = 0; ks < 2; ++ks)
#pragma unroll
            for (int dblk = 0; dblk < 4; ++dblk) {
                const int rb = (dblk*16 + lr)*72 + 32*ks + lg*4;
                s16x4 lo = *(const s16x4*)&lv[cur][rb];
                s16x4 hi = *(const s16x4*)&lv[cur][rb + 16];
                short8 va;
                va[0]=lo[0]; va[1]=lo[1]; va[2]=lo[2]; va[3]=lo[3];
                va[4]=hi[0]; va[5]=hi[1]; va[6]=hi[2]; va[7]=hi[3];
#pragma unroll
                for (int qc = 0; qc < 2; ++qc)
                    ot[dblk][qc] = __builtin_amdgcn_mfma_f32_16x16x32_bf16(va, pb[qc][ks].s, ot[dblk][qc], 0, 0, 0);
            }
        // write next tile into alternate buffer (no conflict with current reads)
        if (has) {
            const int nb = cur ^ 1;
            *(short8*)&lk[nb][r0*72 + c8] = nk0;
            *(short8*)&lv[nb][r0*72 + c8] = nv0;
            *(short8*)&lk[nb][r1*72 + c8] = nk1;
            *(short8*)&lv[nb][r1*72 + c8] = nv1;
            if (tid < 64) lmb[nb][tid] = nm;
        }
        __syncthreads();
        cur ^= 1;
    }
    // epilogue: reduce l across lg, normalize, store O^T -> AO rows
#pragma unroll
    for (int qc = 0; qc < 2; ++qc) {
        float ls = l[qc];
        ls += __shfl_xor(ls, 16);
        ls += __shfl_xor(ls, 32);
        float inv = 1.0f / ls;
        size_t row = (size_t)b*T_ + qbase + qc*16 + lr;
#pragma unroll
        for (int dblk = 0; dblk < 4; ++dblk) {
            unsigned int w0 = cvtpk(ot[dblk][qc][0]*inv, ot[dblk][qc][1]*inv);
            unsigned int w1 = cvtpk(ot[dblk][qc][2]*inv, ot[dblk][qc][3]*inv);
            uint2 pkd; pkd.x = w0; pkd.y = w1;
            *(uint2*)&AO[row * C_ + h*64 + dblk*16 + lg*4] = pkd;
        }
    }
}

extern "C" void kernel_launch(void* const* d_in, const int* in_sizes, int n_in,
                              void* d_out, int out_size, void* d_ws, size_t ws_size,
                              hipStream_t stream) {
    const void* x     = d_in[0];
    const void* mask  = d_in[1];
    const void* wqkv  = d_in[2];
    const void* bqkv  = d_in[3];
    const void* wproj = d_in[4];
    const void* bproj = d_in[5];

    char* ws = (char*)d_ws;
    size_t off = 0;
    auto alloc = [&](size_t bytes) -> void* {
        void* p = ws + off;
        off = (off + bytes + 255) & ~(size_t)255;
        return p;
    };
    int* flags            = (int*)alloc(256);
    unsigned short* Xb    = (unsigned short*)alloc((size_t)BT_ * C_ * 2);
    unsigned short* WqkvT = (unsigned short*)alloc((size_t)C3_ * C_ * 2);
    unsigned short* WprojT= (unsigned short*)alloc((size_t)C_ * C_ * 2);
    float* bqkvF          = (float*)alloc((size_t)C3_ * 4);
    float* bprojF         = (float*)alloc((size_t)C_ * 4);
    float* maskF          = (float*)alloc((size_t)BT_ * 4);
    unsigned short* Qs    = (unsigned short*)alloc((size_t)B_*H_*T_*D_ * 2);
    unsigned short* Ks    = (unsigned short*)alloc((size_t)B_*H_*T_*D_ * 2);
    unsigned short* Vts   = (unsigned short*)alloc((size_t)B_*H_*T_*D_ * 2);
    unsigned short* AO    = (unsigned short*)alloc((size_t)BT_ * C_ * 2);

    k_detect<<<1, 256, 0, stream>>>(x, wqkv, bqkv, wproj, bproj, mask, flags);
    k_canon_x<<<(BT_*C_/8 + 255)/256, 256, 0, stream>>>(x, Xb, flags);
    k_canon_wT<<<dim3(C3_/32, C_/32), 256, 0, stream>>>(wqkv, WqkvT, flags, 1, C_, C3_);
    k_canon_wT<<<dim3(C_/32, C_/32), 256, 0, stream>>>(wproj, WprojT, flags, 3, C_, C_);
    k_canon_small<<<(BT_ + 255)/256, 256, 0, stream>>>(bqkv, bproj, mask, bqkvF, bprojF, maskF, flags);

    // QKV projection -> Q(,K)(,V^T)
    k_gemm<0><<<dim3(C3_/128, BT_/128), 256, 0, stream>>>(
        Xb, WqkvT, bqkvF, Qs, Ks, Vts, BT_, C3_, C_);
    // flash attention (swapped QK^T, log2 softmax, dbuf staging)
    k_attn<<<B_*H_*(T_/128), 256, 0, stream>>>(Qs, Ks, Vts, maskF, AO);
    // output projection -> f32 d_out
    k_gemm<1><<<dim3(C_/128, BT_/128), 256, 0, stream>>>(
        AO, WprojT, bprojF, d_out, nullptr, nullptr, BT_, C_, C_);
}

// Round 8
// 189.989 us; speedup vs baseline: 1.1723x; 1.1723x over previous
//
#include <hip/hip_runtime.h>
#include <stdint.h>

#define B_ 4
#define T_ 2048
#define C_ 768
#define H_ 12
#define D_ 64
#define BT_ (B_*T_)
#define C3_ (3*C_)
#define FMIN_ (-3.402823466e38f)
// 0.125 * log2(e): Q prescale so QK^T scores are in log2 units
#define QSCALE_ (0.18033688f)

typedef __attribute__((ext_vector_type(8))) short short8;
typedef __attribute__((ext_vector_type(4))) short s16x4;
typedef __attribute__((ext_vector_type(4))) float f32x4;

// async global->LDS DMA, 16B per lane; LDS dest = wave-uniform base + lane*16
#define GLDS16(g, l) __builtin_amdgcn_global_load_lds( \
    (const __attribute__((address_space(1))) void*)(g), \
    (__attribute__((address_space(3))) void*)(l), 16, 0, 0)

__device__ __forceinline__ float bf2f(unsigned short u) {
    union { unsigned int i; float f; } v; v.i = ((unsigned int)u) << 16; return v.f;
}
__device__ __forceinline__ unsigned short f2bf(float f) {
    union { float ff; unsigned int i; } v; v.ff = f;
    unsigned int r = v.i + 0x7fffu + ((v.i >> 16) & 1u);
    return (unsigned short)(r >> 16);
}
// packed f32x2 -> bf16x2 (RNE), single HW instr
__device__ __forceinline__ unsigned int cvtpk(float lo, float hi) {
    unsigned int r;
    asm("v_cvt_pk_bf16_f32 %0, %1, %2" : "=v"(r) : "v"(lo), "v"(hi));
    return r;
}
__device__ __forceinline__ float ldf(const void* p, size_t i, int isbf) {
    return isbf ? bf2f(((const unsigned short*)p)[i]) : ((const float*)p)[i];
}

// ---------------- dtype detection, per tensor ----------------
// flags[0..4]: 1 if {x,wqkv,bqkv,wproj,bproj} is bf16, 0 if f32
// flags[5]: mask mode: 1=int32, 2=f32, 0=uint8/bool
__global__ void k_detect(const void* x, const void* wqkv, const void* bqkv,
                         const void* wproj, const void* bproj, const void* mask,
                         int* flags) {
    __shared__ int cnt[8];
    int tid = threadIdx.x;
    if (tid < 8) cnt[tid] = 0;
    __syncthreads();
    const void* ptrs[5] = {x, wqkv, bqkv, wproj, bproj};
#pragma unroll
    for (int t = 0; t < 5; ++t) {
        unsigned short u = ((const unsigned short*)ptrs[t])[2 * tid];
        int e = (u >> 7) & 0xff;
        if (e >= 100 && e <= 140) atomicAdd(&cnt[t], 1);
    }
    if (tid < 64) {
        unsigned int d = ((const unsigned int*)mask)[tid];
        if (d <= 1u) atomicAdd(&cnt[5], 1);
        if (d == 0u || d == 0x3f800000u) atomicAdd(&cnt[6], 1);
    }
    __syncthreads();
    if (tid < 5) flags[tid] = (cnt[tid] >= 128) ? 1 : 0;
    if (tid == 5) flags[5] = (cnt[5] == 64) ? 1 : ((cnt[6] == 64) ? 2 : 0);
}

// ---------------- canonicalize x -> bf16 ----------------
__global__ void k_canon_x(const void* x, unsigned short* xb, const int* flags) {
    const int n8 = BT_ * C_ / 8;
    int i = blockIdx.x * blockDim.x + threadIdx.x;
    if (i >= n8) return;
    if (flags[0]) {
        ((int4*)xb)[i] = ((const int4*)x)[i];
    } else {
        const float4* xf = (const float4*)x;
        float4 a = xf[2*i], b = xf[2*i+1];
        short8 o;
        o[0]=(short)f2bf(a.x); o[1]=(short)f2bf(a.y); o[2]=(short)f2bf(a.z); o[3]=(short)f2bf(a.w);
        o[4]=(short)f2bf(b.x); o[5]=(short)f2bf(b.y); o[6]=(short)f2bf(b.z); o[7]=(short)f2bf(b.w);
        *(short8*)&xb[8*i] = o;
    }
}

// ---------------- transpose weight [K][N] -> bf16 [N][K] ----------------
__global__ void k_canon_wT(const void* src, unsigned short* dst, const int* flags,
                           int fidx, int K, int N) {
    __shared__ float tile[32][33];
    int mode = flags[fidx];
    int n0 = blockIdx.x * 32, k0 = blockIdx.y * 32;
    int tx = threadIdx.x & 31, ty = threadIdx.x >> 5;
    for (int r = ty; r < 32; r += 8) {
        size_t idx = (size_t)(k0 + r) * N + (n0 + tx);
        tile[r][tx] = mode ? bf2f(((const unsigned short*)src)[idx])
                           : ((const float*)src)[idx];
    }
    __syncthreads();
    for (int r = ty; r < 32; r += 8) {
        dst[(size_t)(n0 + r) * K + k0 + tx] = f2bf(tile[tx][r]);
    }
}

// ---------------- biases (f32) + mask bias ----------------
__global__ void k_canon_small(const void* bqkv, const void* bproj, const void* mask,
                              float* bqkvF, float* bprojF, float* maskF, const int* flags) {
    int i = blockIdx.x * blockDim.x + threadIdx.x;
    if (i < C3_) bqkvF[i] = ldf(bqkv, i, flags[2]);
    if (i < C_)  bprojF[i] = ldf(bproj, i, flags[4]);
    if (i < BT_) {
        int mm = flags[5];
        int mv;
        if (mm == 1)      mv = ((const int*)mask)[i] != 0;
        else if (mm == 2) mv = ((const float*)mask)[i] != 0.0f;
        else              mv = ((const unsigned char*)mask)[i] != 0;
        maskF[i] = mv ? FMIN_ : 0.0f;
    }
}

// ---------------- bf16 MFMA GEMM: C = A[M][K] * Bt[N][K]^T + bias ----------------
// Staging via global_load_lds (16B/lane DMA) with BOTH-SIDES XOR swizzle
// (rule #21): LDS dest linear, global source 16B-slot pre-swizzled by ^(row&7),
// ds_read slot ^(row&7) -> conflict-free fragment reads.
// EPI 0: scatter into Q([B,H,T,D], *QSCALE), K([B,H,T,D]), V^T([B,H,D,T]), bf16
// EPI 1: f32 [M][N] into d_out
template<int EPI>
__global__ __launch_bounds__(256) void k_gemm(
        const unsigned short* __restrict__ A, const unsigned short* __restrict__ Bt,
        const float* __restrict__ bias,
        void* __restrict__ out0, unsigned short* __restrict__ out1,
        unsigned short* __restrict__ out2,
        int M, int N, int K) {
    __shared__ __align__(16) unsigned short la[128*64];
    __shared__ __align__(16) unsigned short lb[128*64];
    const int tid = threadIdx.x;
    const int w = tid >> 6, lane = tid & 63, lr = lane & 15, lg = lane >> 4;
    const int wm = (w >> 1) * 64, wn = (w & 1) * 64;
    const int n0 = blockIdx.x * 128, m0 = blockIdx.y * 128;
    // staging coords: chunk of 8 rows x 64 k; lane -> (row_in = lane>>3, slot = lane&7)
    const int rin = lane >> 3;
    const int gslot = (lane & 7) ^ rin;     // pre-swizzled global 16B-slot
    f32x4 acc[4][4] = {};
    for (int k0 = 0; k0 < K; k0 += 64) {
#pragma unroll
        for (int c = 0; c < 4; ++c) {
            const int chunk = w * 4 + c;
            const int row = chunk * 8 + rin;
            GLDS16(&A[(size_t)(m0+row)*K + k0 + gslot*8], &la[chunk*512]);
            GLDS16(&Bt[(size_t)(n0+row)*K + k0 + gslot*8], &lb[chunk*512]);
        }
        __syncthreads();   // implicit vmcnt(0) drains the DMA
#pragma unroll
        for (int ks = 0; ks < 64; ks += 32) {
            short8 af[4], bfr[4];
            const int rs = (lg + (ks >> 3)) ^ (lr & 7);   // swizzled read slot
#pragma unroll
            for (int i = 0; i < 4; ++i)
                af[i] = *(const short8*)&la[(wm + i*16 + lr)*64 + rs*8];
#pragma unroll
            for (int j = 0; j < 4; ++j)
                bfr[j] = *(const short8*)&lb[(wn + j*16 + lr)*64 + rs*8];
#pragma unroll
            for (int i = 0; i < 4; ++i)
#pragma unroll
                for (int j = 0; j < 4; ++j)
                    acc[i][j] = __builtin_amdgcn_mfma_f32_16x16x32_bf16(af[i], bfr[j], acc[i][j], 0, 0, 0);
        }
        __syncthreads();   // all reads done before next-tile DMA
    }
#pragma unroll
    for (int i = 0; i < 4; ++i)
#pragma unroll
        for (int j = 0; j < 4; ++j)
#pragma unroll
            for (int r = 0; r < 4; ++r) {
                int row = m0 + wm + i*16 + lg*4 + r;
                int col = n0 + wn + j*16 + lr;
                float v = acc[i][j][r] + bias[col];
                if (EPI == 0) {
                    int seg = col / C_;
                    int c = col - seg * C_;
                    int h = c >> 6, d = c & 63;
                    int b = row >> 11, t = row & (T_ - 1);
                    if (seg == 0)      ((unsigned short*)out0)[(((size_t)b*H_ + h)*T_ + t)*D_ + d] = f2bf(v * QSCALE_);
                    else if (seg == 1) out1[(((size_t)b*H_ + h)*T_ + t)*D_ + d] = f2bf(v);
                    else               out2[(((size_t)b*H_ + h)*D_ + d)*T_ + t] = f2bf(v);
                } else {
                    ((float*)out0)[(size_t)row * N + col] = v;
                }
            }
}

// ---------------- flash attention, swapped QK^T, log2-domain softmax ----------------
// (round-6 proven structure: single-buffer, two barriers/tile, 18.9KB LDS)
// Q[B,H,T,D] (pre-scaled by 0.125*log2e), K[B,H,T,D], V^T[B,H,D,T], all bf16.
// Block = 4 waves; wave owns 32 q rows. KVBLK = 64.
// S^T = mfma(A=K, B=Q) with C initialized to the per-key mask bias (0 / -FLT_MAX).
// Softmax in log2 domain; defer-max THR=8 (p <= 2^8).
// PV slot-relabeled contraction (P packs in-lane via cvt_pk; V 2x ds_read_b64).
// O accumulates transposed: O^T[d][q], col=q=lr -> rescale lane-uniform.
__global__ __launch_bounds__(256) void k_attn(
        const unsigned short* __restrict__ Q, const unsigned short* __restrict__ Kt,
        const unsigned short* __restrict__ Vt, const float* __restrict__ maskF,
        unsigned short* __restrict__ AO) {
    __shared__ __align__(16) unsigned short lk[64*72];
    __shared__ __align__(16) unsigned short lv[64*72];
    __shared__ __align__(16) float lmb[64];
    const int tid = threadIdx.x;
    const int w = tid >> 6, lane = tid & 63, lr = lane & 15, lg = lane >> 4;
    // bijective XCD swizzle: 768 blocks = 8 XCD x 96; 16 consecutive share one bh's K/V
    const int per = gridDim.x >> 3;
    const int swz = (blockIdx.x & 7) * per + (blockIdx.x >> 3);
    const int bh = swz >> 4, qt = swz & 15;
    const int b = bh / H_, h = bh - b * H_;
    const int qbase = qt * 128 + w * 32;
    const unsigned short* Qb = Q  + (size_t)bh * T_ * D_;
    const unsigned short* Kb = Kt + (size_t)bh * T_ * D_;
    const unsigned short* Vb = Vt + (size_t)bh * D_ * T_;

    // Q as B-operand: lane holds col q=qc*16+lr, k-elems d = dh*32+lg*8..+7
    short8 qf[2][2];
#pragma unroll
    for (int qc = 0; qc < 2; ++qc)
#pragma unroll
        for (int dh = 0; dh < 2; ++dh)
            qf[qc][dh] = *(const short8*)&Qb[(size_t)(qbase + qc*16 + lr) * D_ + dh*32 + lg*8];

    f32x4 ot[4][2] = {};           // O^T[dblk][qc]
    float m[2] = {-INFINITY, -INFINITY}, l[2] = {0.0f, 0.0f};

    for (int kt = 0; kt < T_; kt += 64) {
#pragma unroll
        for (int c = 0; c < 2; ++c) {
            int idx = tid + c * 256;
            int row = idx >> 3, c8 = (idx & 7) * 8;
            *(short8*)&lk[row*72 + c8] = *(const short8*)&Kb[(size_t)(kt + row)*D_ + c8];
            *(short8*)&lv[row*72 + c8] = *(const short8*)&Vb[(size_t)row * T_ + kt + c8];
        }
        if (tid < 64) lmb[tid] = maskF[b*T_ + kt + tid];
        __syncthreads();

        // C-init = mask bias per key (shared by both qc); mask add is free+exact
        f32x4 st[4][2];
#pragma unroll
        for (int kf = 0; kf < 4; ++kf) {
            f32x4 mi = *(const f32x4*)&lmb[kf*16 + lg*4];
            st[kf][0] = mi;
            st[kf][1] = mi;
        }
        // S^T = K Q^T + mask
#pragma unroll
        for (int dh = 0; dh < 2; ++dh) {
            short8 kfr[4];
#pragma unroll
            for (int kf = 0; kf < 4; ++kf)
                kfr[kf] = *(const short8*)&lk[(kf*16 + lr)*72 + dh*32 + lg*8];
#pragma unroll
            for (int kf = 0; kf < 4; ++kf)
#pragma unroll
                for (int qc = 0; qc < 2; ++qc)
                    st[kf][qc] = __builtin_amdgcn_mfma_f32_16x16x32_bf16(kfr[kf], qf[qc][dh], st[kf][qc], 0, 0, 0);
        }
        // online softmax per qc (row = q = qc*16+lr; spread over 4 lanes lg)
#pragma unroll
        for (int qc = 0; qc < 2; ++qc) {
            float t0 = fmaxf(fmaxf(st[0][qc][0], st[0][qc][1]), st[0][qc][2]);
            float t1 = fmaxf(fmaxf(st[0][qc][3], st[1][qc][0]), st[1][qc][1]);
            float t2 = fmaxf(fmaxf(st[1][qc][2], st[1][qc][3]), st[2][qc][0]);
            float t3 = fmaxf(fmaxf(st[2][qc][1], st[2][qc][2]), st[2][qc][3]);
            float t4 = fmaxf(fmaxf(st[3][qc][0], st[3][qc][1]), st[3][qc][2]);
            float tm = fmaxf(fmaxf(t0, t1), fmaxf(fmaxf(t2, t3), fmaxf(t4, st[3][qc][3])));
            tm = fmaxf(tm, __shfl_xor(tm, 16));
            tm = fmaxf(tm, __shfl_xor(tm, 32));
            // defer-max: skip rescale while max growth <= 8 (p bounded by 2^8)
            if (!__all(tm - m[qc] <= 8.0f)) {
                float mn = fmaxf(m[qc], tm);
                float sc = __builtin_amdgcn_exp2f(m[qc] - mn);
                m[qc] = mn;
                l[qc] *= sc;
#pragma unroll
                for (int dblk = 0; dblk < 4; ++dblk) ot[dblk][qc] *= sc;
            }
            float mr = m[qc];
            float ps = 0.0f;
#pragma unroll
            for (int kf = 0; kf < 4; ++kf)
#pragma unroll
                for (int r = 0; r < 4; ++r) {
                    float p = __builtin_amdgcn_exp2f(st[kf][qc][r] - mr);
                    st[kf][qc][r] = p;
                    ps += p;
                }
            l[qc] += ps;
        }
        // pack P in-lane into relabeled B-fragments: pb[qc][ks]
        union PU { unsigned int u[4]; short8 s; };
        PU pb[2][2];
#pragma unroll
        for (int qc = 0; qc < 2; ++qc)
#pragma unroll
            for (int ks = 0; ks < 2; ++ks) {
                pb[qc][ks].u[0] = cvtpk(st[2*ks][qc][0],   st[2*ks][qc][1]);
                pb[qc][ks].u[1] = cvtpk(st[2*ks][qc][2],   st[2*ks][qc][3]);
                pb[qc][ks].u[2] = cvtpk(st[2*ks+1][qc][0], st[2*ks+1][qc][1]);
                pb[qc][ks].u[3] = cvtpk(st[2*ks+1][qc][2], st[2*ks+1][qc][3]);
            }
        // O^T += V^T P^T with matching slot relabel: A-slot (ks,j):
        //   j=0..3 -> key 32ks+lg*4+j ; j=4..7 -> key 32ks+16+lg*4+(j-4)
#pragma unroll
        for (int ks = 0; ks < 2; ++ks)
#pragma unroll
            for (int dblk = 0; dblk < 4; ++dblk) {
                const int rb = (dblk*16 + lr)*72 + 32*ks + lg*4;
                s16x4 lo = *(const s16x4*)&lv[rb];
                s16x4 hi = *(const s16x4*)&lv[rb + 16];
                short8 va;
                va[0]=lo[0]; va[1]=lo[1]; va[2]=lo[2]; va[3]=lo[3];
                va[4]=hi[0]; va[5]=hi[1]; va[6]=hi[2]; va[7]=hi[3];
#pragma unroll
                for (int qc = 0; qc < 2; ++qc)
                    ot[dblk][qc] = __builtin_amdgcn_mfma_f32_16x16x32_bf16(va, pb[qc][ks].s, ot[dblk][qc], 0, 0, 0);
            }
        __syncthreads();
    }
    // epilogue: reduce l across lg, normalize, store O^T -> AO rows
#pragma unroll
    for (int qc = 0; qc < 2; ++qc) {
        float ls = l[qc];
        ls += __shfl_xor(ls, 16);
        ls += __shfl_xor(ls, 32);
        float inv = 1.0f / ls;
        size_t row = (size_t)b*T_ + qbase + qc*16 + lr;
#pragma unroll
        for (int dblk = 0; dblk < 4; ++dblk) {
            unsigned int w0 = cvtpk(ot[dblk][qc][0]*inv, ot[dblk][qc][1]*inv);
            unsigned int w1 = cvtpk(ot[dblk][qc][2]*inv, ot[dblk][qc][3]*inv);
            uint2 pkd; pkd.x = w0; pkd.y = w1;
            *(uint2*)&AO[row * C_ + h*64 + dblk*16 + lg*4] = pkd;
        }
    }
}

extern "C" void kernel_launch(void* const* d_in, const int* in_sizes, int n_in,
                              void* d_out, int out_size, void* d_ws, size_t ws_size,
                              hipStream_t stream) {
    const void* x     = d_in[0];
    const void* mask  = d_in[1];
    const void* wqkv  = d_in[2];
    const void* bqkv  = d_in[3];
    const void* wproj = d_in[4];
    const void* bproj = d_in[5];

    char* ws = (char*)d_ws;
    size_t off = 0;
    auto alloc = [&](size_t bytes) -> void* {
        void* p = ws + off;
        off = (off + bytes + 255) & ~(size_t)255;
        return p;
    };
    int* flags            = (int*)alloc(256);
    unsigned short* Xb    = (unsigned short*)alloc((size_t)BT_ * C_ * 2);
    unsigned short* WqkvT = (unsigned short*)alloc((size_t)C3_ * C_ * 2);
    unsigned short* WprojT= (unsigned short*)alloc((size_t)C_ * C_ * 2);
    float* bqkvF          = (float*)alloc((size_t)C3_ * 4);
    float* bprojF         = (float*)alloc((size_t)C_ * 4);
    float* maskF          = (float*)alloc((size_t)BT_ * 4);
    unsigned short* Qs    = (unsigned short*)alloc((size_t)B_*H_*T_*D_ * 2);
    unsigned short* Ks    = (unsigned short*)alloc((size_t)B_*H_*T_*D_ * 2);
    unsigned short* Vts   = (unsigned short*)alloc((size_t)B_*H_*T_*D_ * 2);
    unsigned short* AO    = (unsigned short*)alloc((size_t)BT_ * C_ * 2);

    k_detect<<<1, 256, 0, stream>>>(x, wqkv, bqkv, wproj, bproj, mask, flags);
    k_canon_x<<<(BT_*C_/8 + 255)/256, 256, 0, stream>>>(x, Xb, flags);
    k_canon_wT<<<dim3(C3_/32, C_/32), 256, 0, stream>>>(wqkv, WqkvT, flags, 1, C_, C3_);
    k_canon_wT<<<dim3(C_/32, C_/32), 256, 0, stream>>>(wproj, WprojT, flags, 3, C_, C_);
    k_canon_small<<<(BT_ + 255)/256, 256, 0, stream>>>(bqkv, bproj, mask, bqkvF, bprojF, maskF, flags);

    // QKV projection -> Q(,K)(,V^T)
    k_gemm<0><<<dim3(C3_/128, BT_/128), 256, 0, stream>>>(
        Xb, WqkvT, bqkvF, Qs, Ks, Vts, BT_, C3_, C_);
    // flash attention (swapped QK^T, log2 softmax)
    k_attn<<<B_*H_*(T_/128), 256, 0, stream>>>(Qs, Ks, Vts, maskF, AO);
    // output projection -> f32 d_out
    k_gemm<1><<<dim3(C_/128, BT_/128), 256, 0, stream>>>(
        AO, WprojT, bprojF, d_out, nullptr, nullptr, BT_, C_, C_);
}